// Round 5
// baseline (543.908 us; speedup 1.0000x reference)
//
#include <hip/hip_runtime.h>
#include <hip/hip_fp16.h>
#include <cstdint>
#include <math.h>

#define INP  3072
#define HID  1024
#define OUTD 768
#define BSZ  8192

typedef _Float16 f16;
typedef _Float16 f16x8 __attribute__((ext_vector_type(8)));
typedef _Float16 f16x4 __attribute__((ext_vector_type(4)));
typedef float    f32x4 __attribute__((ext_vector_type(4)));
typedef int      i32x4 __attribute__((ext_vector_type(4)));
typedef signed char s8;

static constexpr float LOG2E = 1.44269504088896340736f;
static constexpr float LN2   = 0.69314718055994530942f;
static constexpr float QS    = 384.0f;
static constexpr float CSC   = LOG2E / (QS * QS);

// ---------------- workspace layout (bytes) ----------------
static constexpr size_t OFF_XH   = 0;
static constexpr size_t OFF_PN   = 0;                            // packed i8
static constexpr size_t OFF_YN   = OFF_PN   + (size_t)BSZ*OUTD;  // packed i8
static constexpr size_t OFF_PSUM = OFF_YN   + (size_t)BSZ*OUTD;
static constexpr size_t OFF_PMAX = OFF_PSUM + (size_t)BSZ*64*4;
static constexpr size_t OFF_HB   = OFF_XH   + (size_t)BSZ*INP*2;
static constexpr size_t OFF_TT   = OFF_HB   + (size_t)BSZ*HID*2;
static constexpr size_t OFF_W1T  = OFF_TT   + (size_t)BSZ*OUTD*4;
static constexpr size_t OFF_WAT  = OFF_W1T  + (size_t)INP*HID*2;
static constexpr size_t OFF_WBT  = OFF_WAT  + (size_t)HID*HID*2;
static constexpr size_t OFF_W2T  = OFF_WBT  + (size_t)HID*HID*2;
static constexpr size_t OFF_DIAG = OFF_W2T  + (size_t)HID*OUTD*2;
static constexpr size_t OFF_ACC  = OFF_DIAG + (size_t)BSZ*4;

// Packed fragment-major layouts:
//  f16 weights: elem offset = ((n>>4)*(K>>3) + (k>>3))*128 + (n&15)*8 + (k&7)
//  i8 pn/yn:    byte offset = ((r>>4)*48   + (k>>4))*256 + (r&15)*16 + (k&15)
// => per-lane MFMA fragment address = rowblock/chunk-uniform base + lane*16B.

#define GL2LDS(gp, lp) __builtin_amdgcn_global_load_lds( \
    (__attribute__((address_space(1))) void*)(uintptr_t)(gp), \
    (__attribute__((address_space(3))) void*)(unsigned)(uintptr_t)(lp), 16, 0, 0)

__device__ __forceinline__ float blk_sum256(float v, float* sm) {
  #pragma unroll
  for (int d = 1; d < 64; d <<= 1) v += __shfl_xor(v, d, 64);
  int tid = threadIdx.x;
  __syncthreads();
  if ((tid & 63) == 0) sm[tid >> 6] = v;
  __syncthreads();
  return sm[0] + sm[1] + sm[2] + sm[3];
}

__device__ __forceinline__ s8 q8(float v) {
  int q = __float2int_rn(v * QS);
  q = q > 127 ? 127 : (q < -127 ? -127 : q);
  return (s8)q;
}

// ---------------- LN1 (float4) ----------------
__global__ __launch_bounds__(256) void ln1_kernel(const float* __restrict__ inp,
    const float* __restrict__ g, const float* __restrict__ b, f16* __restrict__ xh) {
  __shared__ float sm[4];
  const int row = blockIdx.x, tid = threadIdx.x;
  const float4* x4 = (const float4*)(inp + (size_t)row * INP);
  float4 v[3]; float s = 0.f;
  #pragma unroll
  for (int i = 0; i < 3; i++) { v[i] = x4[tid + i*256]; s += v[i].x+v[i].y+v[i].z+v[i].w; }
  const float mean = blk_sum256(s, sm) * (1.f/INP);
  float s2 = 0.f;
  #pragma unroll
  for (int i = 0; i < 3; i++) {
    float dx=v[i].x-mean, dy=v[i].y-mean, dz=v[i].z-mean, dw=v[i].w-mean;
    s2 += dx*dx+dy*dy+dz*dz+dw*dw;
  }
  const float rstd = rsqrtf(blk_sum256(s2, sm) * (1.f/INP) + 1e-5f);
  const float4* g4p = (const float4*)g;
  const float4* b4p = (const float4*)b;
  f16x4* o4 = (f16x4*)(xh + (size_t)row * INP);
  #pragma unroll
  for (int i = 0; i < 3; i++) {
    const int c = tid + i*256;
    const float4 gg = g4p[c], bb = b4p[c];
    f16x4 t;
    t[0] = (f16)((v[i].x-mean)*rstd*gg.x + bb.x);
    t[1] = (f16)((v[i].y-mean)*rstd*gg.y + bb.y);
    t[2] = (f16)((v[i].z-mean)*rstd*gg.z + bb.z);
    t[3] = (f16)((v[i].w-mean)*rstd*gg.w + bb.w);
    o4[c] = t;
  }
}

// ------------- weight transpose + cast + fragment-major pack -------------
__global__ __launch_bounds__(256) void transpose_pack(
    const float* __restrict__ W1, const float* __restrict__ Wa,
    const float* __restrict__ Wb, const float* __restrict__ W2,
    f16* __restrict__ W1T, f16* __restrict__ WAT,
    f16* __restrict__ WBT, f16* __restrict__ W2T) {
  __shared__ float t[32][33];
  const int bI = blockIdx.x;
  const float* W; f16* Wt; int K, N, n0, k0;
  if (bI < 3072)      { int tt = bI;      W = W1; Wt = W1T; K = INP; N = HID;  n0 = (tt & 31)*32; k0 = (tt >> 5)*32; }
  else if (bI < 4096) { int tt = bI-3072; W = Wa; Wt = WAT; K = HID; N = HID;  n0 = (tt & 31)*32; k0 = (tt >> 5)*32; }
  else if (bI < 5120) { int tt = bI-4096; W = Wb; Wt = WBT; K = HID; N = HID;  n0 = (tt & 31)*32; k0 = (tt >> 5)*32; }
  else                { int tt = bI-5120; W = W2; Wt = W2T; K = HID; N = OUTD; int kq = tt/24; n0 = (tt - kq*24)*32; k0 = kq*32; }
  const int tx = threadIdx.x & 31, ty = threadIdx.x >> 5;
  #pragma unroll
  for (int i = 0; i < 32; i += 8) t[ty+i][tx] = W[(size_t)(k0+ty+i)*N + n0+tx];  // t[k_l][n_l]
  __syncthreads();
  const int tid = threadIdx.x;
  if (tid < 128) {
    const int fm = tid & 15, half = (tid >> 4) & 1, kc = tid >> 5;  // kc 0..3
    const int n_l = half*16 + fm;
    f16x8 v;
    #pragma unroll
    for (int e = 0; e < 8; e++) v[e] = (f16)t[kc*8 + e][n_l];
    const int n_g = n0 + n_l;
    const size_t off = ((size_t)(n_g >> 4)*(K >> 3) + (k0 >> 3) + kc)*128 + fm*8;
    *(f16x8*)(Wt + off) = v;
  }
}

// ------------- LN2+normalize+quantize(packed) & yn quantize(packed) -------------
__global__ __launch_bounds__(256) void ln2_yn(const float* __restrict__ pre,
    const float* __restrict__ g, const float* __restrict__ b,
    const float* __restrict__ y,
    float* __restrict__ outY, s8* __restrict__ pn, s8* __restrict__ yn) {
  __shared__ float sm[4];
  const int tid = threadIdx.x;
  if ((int)blockIdx.x < BSZ) {
    const int row = blockIdx.x;
    const float* x = pre + (size_t)row * OUTD;
    float v[3]; float s = 0.f;
    #pragma unroll
    for (int i = 0; i < 3; i++) { v[i] = x[tid + i*256]; s += v[i]; }
    const float mean = blk_sum256(s, sm) * (1.f/OUTD);
    float s2 = 0.f;
    #pragma unroll
    for (int i = 0; i < 3; i++) { float d = v[i]-mean; s2 += d*d; }
    const float rstd = rsqrtf(blk_sum256(s2, sm) * (1.f/OUTD) + 1e-5f);
    float z[3]; float n2 = 0.f;
    #pragma unroll
    for (int i = 0; i < 3; i++) { int c = tid + i*256; z[i] = (v[i]-mean)*rstd*g[c] + b[c]; n2 += z[i]*z[i]; }
    const float rn = rsqrtf(blk_sum256(n2, sm));
    float* oy = outY + (size_t)row * OUTD;
    const size_t rbase = (size_t)(row >> 4)*48*256 + (row & 15)*16;
    #pragma unroll
    for (int i = 0; i < 3; i++) {
      const int c = tid + i*256;
      oy[c] = z[i];
      pn[rbase + (size_t)(c >> 4)*256 + (c & 15)] = q8(z[i]*rn);
    }
  } else {
    const int row = blockIdx.x - BSZ;
    const float* x = y + (size_t)row * OUTD;
    float v[3]; float n2 = 0.f;
    #pragma unroll
    for (int i = 0; i < 3; i++) { v[i] = x[tid + i*256]; n2 += v[i]*v[i]; }
    const float rn = rsqrtf(blk_sum256(n2, sm));
    const size_t rbase = (size_t)(row >> 4)*48*256 + (row & 15)*16;
    #pragma unroll
    for (int i = 0; i < 3; i++) {
      const int c = tid + i*256;
      yn[rbase + (size_t)(c >> 4)*256 + (c & 15)] = q8(v[i]*rn);
    }
  }
}

// ------------- backbone f16 GEMM: A in LDS (BK=64), B direct packed -------------
#define EPI_H   0
#define EPI_T   1
#define EPI_RES 2
#define EPI_P   3

template<int EPI>
__global__ __launch_bounds__(256) void gemm_bt(
    const f16* __restrict__ A, const f16* __restrict__ Bpk, int K, int N,
    const float* __restrict__ bias, float* __restrict__ Cf, f16* __restrict__ Ch,
    const f16* __restrict__ Hin)
{
  __shared__ alignas(16) f16 lA[2][128*64];   // 32 KB total
  const int tid  = threadIdx.x;
  const int wave = tid >> 6, lane = tid & 63;
  const int n0 = blockIdx.x * 128;   // x = n: 8 n-blocks round-robin onto 8 XCDs
  const int m0 = blockIdx.y * 128;
  const int Kc = K >> 3;
  // A staging: wave stages rows [wave*32, +32): 4 insts of 8 rows x 8x16B chunks.
  // Swizzle: LDS chunk c holds global chunk c ^ (row&7); row&7 == lane>>3 here.
  const int sr8 = lane >> 3;
  const int scg = (lane & 7) ^ sr8;
  const f16* gA = A + (size_t)(m0 + wave*32 + sr8) * K + scg*8;
  const int wm = wave & 1, wn = wave >> 1;
  const int fm = lane & 15;
  const int g4 = lane >> 4;
  const f16* pB = Bpk + (size_t)lane * 8;   // per-lane fragment base

  f32x4 acc[4][4];
  #pragma unroll
  for (int i = 0; i < 4; i++)
    #pragma unroll
    for (int j = 0; j < 4; j++) acc[i][j] = (f32x4){0.f,0.f,0.f,0.f};

  auto stageA = [&](int buf, int it) {
    f16* d = &lA[buf][wave*32*64];
    const f16* g = gA + it*64;
    #pragma unroll
    for (int q = 0; q < 4; q++) GL2LDS(g + (size_t)q*8*K, d + q*8*64);
  };
  auto loadB = [&](f16x8 (*bf)[4], int it) {
    #pragma unroll
    for (int j = 0; j < 4; j++) {
      const size_t nb = (size_t)(n0 >> 4) + wn*4 + j;
      const f16* base = pB + (nb*Kc + (size_t)it*8)*128;
      bf[0][j] = *(const f16x8*)(base);
      bf[1][j] = *(const f16x8*)(base + 4*128);
    }
  };
  auto computeStep = [&](const f16* lAc, f16x8 (*bf)[4]) {
    #pragma unroll
    for (int h = 0; h < 2; h++) {
      f16x8 af[4];
      #pragma unroll
      for (int i = 0; i < 4; i++)
        af[i] = *(const f16x8*)&lAc[(wm*64 + i*16 + fm)*64 + (((h*4+g4) ^ (fm & 7))*8)];
      #pragma unroll
      for (int i = 0; i < 4; i++)
        #pragma unroll
        for (int j = 0; j < 4; j++)
          acc[i][j] = __builtin_amdgcn_mfma_f32_16x16x32_f16(af[i], bf[h][j], acc[i][j], 0, 0, 0);
    }
  };

  f16x8 bfA[2][4], bfB[2][4];
  const int iters = K >> 6;   // even for all call sites (48/16/16)
  stageA(0, 0); loadB(bfA, 0);
  __syncthreads();
  for (int it = 0; it < iters; it += 2) {
    if (it + 1 < iters) { stageA(1, it + 1); loadB(bfB, it + 1); }
    computeStep(&lA[0][0], bfA);
    __syncthreads();
    if (it + 2 < iters) { stageA(0, it + 2); loadB(bfA, it + 2); }
    computeStep(&lA[1][0], bfB);
    __syncthreads();
  }

  // C/D layout: col = lane&15, row = (lane>>4)*4 + reg
  const int colb = n0 + wn*64;
  const int rowb = m0 + wm*64;
  #pragma unroll
  for (int i = 0; i < 4; i++) {
    #pragma unroll
    for (int j = 0; j < 4; j++) {
      const int col = colb + j*16 + fm;
      const float bs = bias[col];
      #pragma unroll
      for (int r = 0; r < 4; r++) {
        const int row = rowb + i*16 + g4*4 + r;
        float v = acc[i][j][r] + bs;
        const size_t idx = (size_t)row * N + col;
        if constexpr (EPI == EPI_H)        { Ch[idx] = (f16)v; }
        else if constexpr (EPI == EPI_T)   { v = fmaxf(v, 0.f); Ch[idx] = (f16)v; }
        else if constexpr (EPI == EPI_RES) { v = fmaxf(v, 0.f); v += (float)Hin[idx]; Ch[idx] = (f16)v; }
        else                               { Cf[idx] = v; }
      }
    }
  }
}

// ------------- int8 S-GEMM: NO LDS in K-loop, packed direct frags -------------
__global__ __launch_bounds__(256) void gemm_s8(
    const s8* __restrict__ Apk, const s8* __restrict__ Bpk,
    float* __restrict__ partsum, float* __restrict__ partmax, float* __restrict__ diagv)
{
  __shared__ float redS[2][128], redM[2][128];
  const int tid = threadIdx.x;
  const int wave = tid >> 6, lane = tid & 63;
  // XCD swizzle: consecutive blocks round-robin XCDs; give each XCD an n-slab
  // (8 n-blocks = 768 KB of yn, L2-resident) and stream all m through it.
  const int lin = blockIdx.x;
  const int xcd = lin & 7, p = lin >> 3;
  const int mb = p & 63, nb = (xcd << 3) + (p >> 6);
  const int m0 = mb * 128, n0 = nb * 128;
  const int wm = wave & 1, wn = wave >> 1;
  const int fm = lane & 15;
  const int g4 = lane >> 4;
  const s8* pA = Apk + (size_t)lane * 16;
  const s8* pB = Bpk + (size_t)lane * 16;

  i32x4 acc[4][4];
  #pragma unroll
  for (int i = 0; i < 4; i++)
    #pragma unroll
    for (int j = 0; j < 4; j++) acc[i][j] = (i32x4){0,0,0,0};

  auto loadA = [&](i32x4* af, int it) {
    #pragma unroll
    for (int i = 0; i < 4; i++)
      af[i] = *(const i32x4*)(pA + ((size_t)(mb*8 + wm*4 + i)*48 + it*4)*256);
  };
  auto loadB = [&](i32x4* bf, int it) {
    #pragma unroll
    for (int j = 0; j < 4; j++)
      bf[j] = *(const i32x4*)(pB + ((size_t)(nb*8 + wn*4 + j)*48 + it*4)*256);
  };
  auto mf = [&](i32x4* af, i32x4* bf) {
    #pragma unroll
    for (int i = 0; i < 4; i++)
      #pragma unroll
      for (int j = 0; j < 4; j++)
        acc[i][j] = __builtin_amdgcn_mfma_i32_16x16x64_i8(af[i], bf[j], acc[i][j], 0, 0, 0);
  };

  i32x4 af0[4], bf0[4], af1[4], bf1[4];
  loadA(af0, 0); loadB(bf0, 0);
  for (int it = 0; it < 12; it += 2) {
    loadA(af1, it + 1); loadB(bf1, it + 1);
    mf(af0, bf0);
    if (it + 2 < 12) { loadA(af0, it + 2); loadB(bf0, it + 2); }
    mf(af1, bf1);
  }

  if (mb == nb) {
    #pragma unroll
    for (int i = 0; i < 4; i++)
      #pragma unroll
      for (int j = 0; j < 4; j++) {
        const int col = n0 + wn*64 + j*16 + fm;
        #pragma unroll
        for (int r = 0; r < 4; r++) {
          const int row = m0 + wm*64 + i*16 + g4*4 + r;
          if (row == col) diagv[row] = (float)acc[i][j][r] * CSC;
        }
      }
  }
  #pragma unroll
  for (int i = 0; i < 4; i++) {
    #pragma unroll
    for (int r = 0; r < 4; r++) {
      const float a0 = (float)acc[i][0][r] * CSC;
      const float a1 = (float)acc[i][1][r] * CSC;
      const float a2 = (float)acc[i][2][r] * CSC;
      const float a3 = (float)acc[i][3][r] * CSC;
      float s  = exp2f(a0) + exp2f(a1) + exp2f(a2) + exp2f(a3);
      float mx = fmaxf(fmaxf(a0, a1), fmaxf(a2, a3));
      #pragma unroll
      for (int d = 1; d < 16; d <<= 1) {
        s  += __shfl_xor(s, d, 64);
        mx  = fmaxf(mx, __shfl_xor(mx, d, 64));
      }
      if (fm == 0) { const int lrow = wm*64 + i*16 + g4*4 + r; redS[wn][lrow] = s; redM[wn][lrow] = mx; }
    }
  }
  __syncthreads();
  if (tid < 128) {
    const float sa = redS[0][tid] + redS[1][tid];
    const float ma = fmaxf(redM[0][tid], redM[1][tid]);
    const size_t pidx = (size_t)nb * BSZ + m0 + tid;
    partsum[pidx] = sa; partmax[pidx] = ma;
  }
}

// ---------------- final reduce + inlined finalize ----------------
__global__ __launch_bounds__(256) void reduce_rows(const float* __restrict__ partsum,
    const float* __restrict__ partmax, const float* __restrict__ diagv,
    float* __restrict__ accum, float* __restrict__ out) {
  __shared__ float sm[4];
  const int row = blockIdx.x*256 + threadIdx.x;
  float s = 0.f, mx = -1e30f;
  for (int i = 0; i < 64; i++) {
    s  += partsum[(size_t)i*BSZ + row];
    mx  = fmaxf(mx, partmax[(size_t)i*BSZ + row]);
  }
  const float dgs  = diagv[row];
  const float corr = (dgs >= mx) ? 1.f : 0.f;
  const float lse  = logf(s);
  const float dg   = dgs * LN2;
  const float lse_s = blk_sum256(lse, sm);
  const float dg_s  = blk_sum256(dg, sm);
  const float c_s   = blk_sum256(corr, sm);
  if (threadIdx.x == 0) {
    atomicAdd(&accum[0], lse_s);
    atomicAdd(&accum[1], dg_s);
    atomicAdd(&accum[2], c_s);
    __threadfence();
    const unsigned old = atomicAdd((unsigned*)&accum[3], 1u);
    if (old == gridDim.x - 1) {
      const float a0 = atomicAdd(&accum[0], 0.f);
      const float a1 = atomicAdd(&accum[1], 0.f);
      const float a2 = atomicAdd(&accum[2], 0.f);
      out[0] = a0 - a1;
      out[1] = a2 * (1.f / BSZ);
    }
  }
}

// ---------------- launch ----------------
extern "C" void kernel_launch(void* const* d_in, const int* in_sizes, int n_in,
                              void* d_out, int out_size, void* d_ws, size_t ws_size,
                              hipStream_t stream) {
  const float* inp  = (const float*)d_in[0];
  const float* y    = (const float*)d_in[1];
  const float* ln1g = (const float*)d_in[2];
  const float* ln1b = (const float*)d_in[3];
  const float* W1   = (const float*)d_in[4];
  const float* b1   = (const float*)d_in[5];
  const float* Wa   = (const float*)d_in[6];
  const float* ba   = (const float*)d_in[7];
  const float* Wb   = (const float*)d_in[8];
  const float* bb   = (const float*)d_in[9];
  const float* W2   = (const float*)d_in[10];
  const float* b2   = (const float*)d_in[11];
  const float* ln2g = (const float*)d_in[12];
  const float* ln2b = (const float*)d_in[13];
  float* out = (float*)d_out;

  char* ws = (char*)d_ws;
  f16*   XH   = (f16*)  (ws + OFF_XH);
  s8*    PN   = (s8*)   (ws + OFF_PN);
  s8*    YN   = (s8*)   (ws + OFF_YN);
  float* PSUM = (float*)(ws + OFF_PSUM);
  float* PMAX = (float*)(ws + OFF_PMAX);
  f16*   HB   = (f16*)  (ws + OFF_HB);
  f16*   T    = (f16*)  (ws + OFF_TT);
  float* PRE2 = (float*)(ws + OFF_TT);
  f16*   W1T  = (f16*)  (ws + OFF_W1T);
  f16*   WAT  = (f16*)  (ws + OFF_WAT);
  f16*   WBT  = (f16*)  (ws + OFF_WBT);
  f16*   W2T  = (f16*)  (ws + OFF_W2T);
  float* DIAG = (float*)(ws + OFF_DIAG);
  float* ACC  = (float*)(ws + OFF_ACC);

  transpose_pack<<<5888, 256, 0, stream>>>(W1, Wa, Wb, W2, W1T, WAT, WBT, W2T);
  ln1_kernel<<<BSZ, 256, 0, stream>>>(inp, ln1g, ln1b, XH);

  // grid.x = n-blocks (round-robin onto XCDs => weight slab per XCD in L2)
  gemm_bt<EPI_H><<<dim3(HID/128, BSZ/128), 256, 0, stream>>>(
      XH, W1T, INP, HID, b1, nullptr, HB, nullptr);

  for (int it = 0; it < 2; it++) {
    gemm_bt<EPI_T><<<dim3(HID/128, BSZ/128), 256, 0, stream>>>(
        HB, WAT, HID, HID, ba, nullptr, T, nullptr);
    gemm_bt<EPI_RES><<<dim3(HID/128, BSZ/128), 256, 0, stream>>>(
        T, WBT, HID, HID, bb, nullptr, HB, HB);
  }

  gemm_bt<EPI_P><<<dim3(OUTD/128, BSZ/128), 256, 0, stream>>>(
      HB, W2T, HID, OUTD, b2, PRE2, nullptr, nullptr);

  ln2_yn<<<2*BSZ, 256, 0, stream>>>(PRE2, ln2g, ln2b, y, out, PN, YN);

  hipMemsetAsync(ACC, 0, 4*sizeof(float), stream);

  gemm_s8<<<4096, 256, 0, stream>>>(PN, YN, PSUM, PMAX, DIAG);

  reduce_rows<<<BSZ/256, 256, 0, stream>>>(PSUM, PMAX, DIAG, ACC, out + (size_t)BSZ*OUTD);
}

// Round 6
// 503.379 us; speedup vs baseline: 1.0805x; 1.0805x over previous
//
#include <hip/hip_runtime.h>
#include <hip/hip_fp16.h>
#include <cstdint>
#include <math.h>

#define INP  3072
#define HID  1024
#define OUTD 768
#define BSZ  8192

typedef _Float16 f16;
typedef _Float16 f16x8 __attribute__((ext_vector_type(8)));
typedef _Float16 f16x4 __attribute__((ext_vector_type(4)));
typedef float    f32x4 __attribute__((ext_vector_type(4)));
typedef int      i32x4 __attribute__((ext_vector_type(4)));
typedef signed char s8;

static constexpr float LOG2E = 1.44269504088896340736f;
static constexpr float LN2   = 0.69314718055994530942f;
static constexpr float QS    = 384.0f;
static constexpr float CSC   = LOG2E / (QS * QS);

// ---------------- workspace layout (bytes) ----------------
static constexpr size_t OFF_XH   = 0;
static constexpr size_t OFF_PN   = 0;                            // i8 [8192][768] row-major
static constexpr size_t OFF_YN   = OFF_PN   + (size_t)BSZ*OUTD;
static constexpr size_t OFF_PSUM = OFF_YN   + (size_t)BSZ*OUTD;
static constexpr size_t OFF_PMAX = OFF_PSUM + (size_t)BSZ*64*4;
static constexpr size_t OFF_HB   = OFF_XH   + (size_t)BSZ*INP*2;
static constexpr size_t OFF_TT   = OFF_HB   + (size_t)BSZ*HID*2;
static constexpr size_t OFF_W1T  = OFF_TT   + (size_t)BSZ*OUTD*4;
static constexpr size_t OFF_WAT  = OFF_W1T  + (size_t)INP*HID*2;
static constexpr size_t OFF_WBT  = OFF_WAT  + (size_t)HID*HID*2;
static constexpr size_t OFF_W2T  = OFF_WBT  + (size_t)HID*HID*2;
static constexpr size_t OFF_DIAG = OFF_W2T  + (size_t)HID*OUTD*2;
static constexpr size_t OFF_ACC  = OFF_DIAG + (size_t)BSZ*4;

#define GL2LDS(gp, lp) __builtin_amdgcn_global_load_lds( \
    (__attribute__((address_space(1))) void*)(uintptr_t)(gp), \
    (__attribute__((address_space(3))) void*)(unsigned)(uintptr_t)(lp), 16, 0, 0)

__device__ __forceinline__ float blk_sum256(float v, float* sm) {
  #pragma unroll
  for (int d = 1; d < 64; d <<= 1) v += __shfl_xor(v, d, 64);
  int tid = threadIdx.x;
  __syncthreads();
  if ((tid & 63) == 0) sm[tid >> 6] = v;
  __syncthreads();
  return sm[0] + sm[1] + sm[2] + sm[3];
}

__device__ __forceinline__ s8 q8(float v) {
  int q = __float2int_rn(v * QS);
  q = q > 127 ? 127 : (q < -127 ? -127 : q);
  return (s8)q;
}

// ---------------- LN1 (float4) ----------------
__global__ __launch_bounds__(256) void ln1_kernel(const float* __restrict__ inp,
    const float* __restrict__ g, const float* __restrict__ b, f16* __restrict__ xh) {
  __shared__ float sm[4];
  const int row = blockIdx.x, tid = threadIdx.x;
  const float4* x4 = (const float4*)(inp + (size_t)row * INP);
  float4 v[3]; float s = 0.f;
  #pragma unroll
  for (int i = 0; i < 3; i++) { v[i] = x4[tid + i*256]; s += v[i].x+v[i].y+v[i].z+v[i].w; }
  const float mean = blk_sum256(s, sm) * (1.f/INP);
  float s2 = 0.f;
  #pragma unroll
  for (int i = 0; i < 3; i++) {
    float dx=v[i].x-mean, dy=v[i].y-mean, dz=v[i].z-mean, dw=v[i].w-mean;
    s2 += dx*dx+dy*dy+dz*dz+dw*dw;
  }
  const float rstd = rsqrtf(blk_sum256(s2, sm) * (1.f/INP) + 1e-5f);
  const float4* g4p = (const float4*)g;
  const float4* b4p = (const float4*)b;
  f16x4* o4 = (f16x4*)(xh + (size_t)row * INP);
  #pragma unroll
  for (int i = 0; i < 3; i++) {
    const int c = tid + i*256;
    const float4 gg = g4p[c], bb = b4p[c];
    f16x4 t;
    t[0] = (f16)((v[i].x-mean)*rstd*gg.x + bb.x);
    t[1] = (f16)((v[i].y-mean)*rstd*gg.y + bb.y);
    t[2] = (f16)((v[i].z-mean)*rstd*gg.z + bb.z);
    t[3] = (f16)((v[i].w-mean)*rstd*gg.w + bb.w);
    o4[c] = t;
  }
}

// ---------------- all 4 weight transposes in one launch ----------------
__global__ __launch_bounds__(256) void transpose_all(
    const float* __restrict__ W1, const float* __restrict__ Wa,
    const float* __restrict__ Wb, const float* __restrict__ W2,
    f16* __restrict__ W1T, f16* __restrict__ WAT,
    f16* __restrict__ WBT, f16* __restrict__ W2T) {
  __shared__ float t[32][33];
  const int bI = blockIdx.x;
  const float* W; f16* Wt; int K, N, n0, k0;
  if (bI < 3072)      { int tt = bI;      W = W1; Wt = W1T; K = INP; N = HID;  n0 = (tt & 31)*32; k0 = (tt >> 5)*32; }
  else if (bI < 4096) { int tt = bI-3072; W = Wa; Wt = WAT; K = HID; N = HID;  n0 = (tt & 31)*32; k0 = (tt >> 5)*32; }
  else if (bI < 5120) { int tt = bI-4096; W = Wb; Wt = WBT; K = HID; N = HID;  n0 = (tt & 31)*32; k0 = (tt >> 5)*32; }
  else                { int tt = bI-5120; W = W2; Wt = W2T; K = HID; N = OUTD; int kq = tt/24; n0 = (tt - kq*24)*32; k0 = kq*32; }
  const int tx = threadIdx.x & 31, ty = threadIdx.x >> 5;
  #pragma unroll
  for (int i = 0; i < 32; i += 8) t[ty+i][tx] = W[(size_t)(k0+ty+i)*N + n0+tx];
  __syncthreads();
  #pragma unroll
  for (int i = 0; i < 32; i += 8) Wt[(size_t)(n0+ty+i)*K + k0+tx] = (f16)t[tx][ty+i];
}

// ---------------- LN2+normalize+quantize & yn quantize (row-major) ----------------
__global__ __launch_bounds__(256) void ln2_yn(const float* __restrict__ pre,
    const float* __restrict__ g, const float* __restrict__ b,
    const float* __restrict__ y,
    float* __restrict__ outY, s8* __restrict__ pn, s8* __restrict__ yn) {
  __shared__ float sm[4];
  const int tid = threadIdx.x;
  if ((int)blockIdx.x < BSZ) {
    const int row = blockIdx.x;
    const float* x = pre + (size_t)row * OUTD;
    float v[3]; float s = 0.f;
    #pragma unroll
    for (int i = 0; i < 3; i++) { v[i] = x[tid + i*256]; s += v[i]; }
    const float mean = blk_sum256(s, sm) * (1.f/OUTD);
    float s2 = 0.f;
    #pragma unroll
    for (int i = 0; i < 3; i++) { float d = v[i]-mean; s2 += d*d; }
    const float rstd = rsqrtf(blk_sum256(s2, sm) * (1.f/OUTD) + 1e-5f);
    float z[3]; float n2 = 0.f;
    #pragma unroll
    for (int i = 0; i < 3; i++) { int c = tid + i*256; z[i] = (v[i]-mean)*rstd*g[c] + b[c]; n2 += z[i]*z[i]; }
    const float rn = rsqrtf(blk_sum256(n2, sm));
    float* oy = outY + (size_t)row * OUTD;
    s8*   op = pn   + (size_t)row * OUTD;
    #pragma unroll
    for (int i = 0; i < 3; i++) { int c = tid + i*256; oy[c] = z[i]; op[c] = q8(z[i]*rn); }
  } else {
    const int row = blockIdx.x - BSZ;
    const float* x = y + (size_t)row * OUTD;
    float v[3]; float n2 = 0.f;
    #pragma unroll
    for (int i = 0; i < 3; i++) { v[i] = x[tid + i*256]; n2 += v[i]*v[i]; }
    const float rn = rsqrtf(blk_sum256(n2, sm));
    s8* o = yn + (size_t)row * OUTD;
    #pragma unroll
    for (int i = 0; i < 3; i++) { int c = tid + i*256; o[c] = q8(v[i]*rn); }
  }
}

// ------------- backbone f16 GEMM: 128x128 tile, BK=64, LDS dbuf -------------
// Row geometry: 128 B/row (64 f16), 8 chunks of 16 B. XOR swizzle: LDS chunk c
// holds global chunk c^(row&7); read chunk (h*4+g4)^(fm&7). Quarter-wave covers
// all 32 banks (fm 0..7) with fm 8..15 as free 2-way aliases.
#define EPI_H   0
#define EPI_T   1
#define EPI_RES 2
#define EPI_P   3

template<int EPI>
__global__ __launch_bounds__(256) void gemm_bt(
    const f16* __restrict__ A, const f16* __restrict__ B, int K, int N,
    const float* __restrict__ bias, float* __restrict__ Cf, f16* __restrict__ Ch,
    const f16* __restrict__ Hin)
{
  __shared__ alignas(16) f16 lA[2][128*64];   // 32 KB
  __shared__ alignas(16) f16 lB[2][128*64];   // 32 KB
  const int tid  = threadIdx.x;
  const int wave = tid >> 6, lane = tid & 63;
  const int m0 = blockIdx.x * 128, n0 = blockIdx.y * 128;
  const int r8 = lane >> 3;          // staging row-within-8
  const int c8 = lane & 7;           // staging chunk
  const int cg = c8 ^ r8;            // global chunk (swizzled)
  // wave stages rows [wave*32, wave*32+32) of both operands, 4 insts each
  const f16* gA = A + (size_t)(m0 + wave*32 + r8) * K + cg*8;
  const f16* gB = B + (size_t)(n0 + wave*32 + r8) * K + cg*8;
  const int wm = wave & 1, wn = wave >> 1;
  const int fm = lane & 15;
  const int g4 = lane >> 4;
  const int fsw = fm & 7;

  f32x4 acc[4][4];
  #pragma unroll
  for (int i = 0; i < 4; i++)
    #pragma unroll
    for (int j = 0; j < 4; j++) acc[i][j] = (f32x4){0.f,0.f,0.f,0.f};

  const int iters = K >> 6;
  auto stage = [&](int buf, int it) {
    f16* dA = &lA[buf][wave*32*64];
    f16* dB = &lB[buf][wave*32*64];
    const f16* sA = gA + it*64;
    const f16* sB = gB + it*64;
    #pragma unroll
    for (int q = 0; q < 4; q++) {
      GL2LDS(sA + (size_t)q*8*K, dA + q*8*64);
      GL2LDS(sB + (size_t)q*8*K, dB + q*8*64);
    }
  };

  stage(0, 0);
  __syncthreads();
  for (int it = 0; it < iters; ++it) {
    const int cur = it & 1;
    if (it + 1 < iters) stage(cur ^ 1, it + 1);
    #pragma unroll
    for (int h = 0; h < 2; h++) {
      const int ck = ((h*4 + g4) ^ fsw) * 8;
      f16x8 af[4], bf[4];
      #pragma unroll
      for (int i = 0; i < 4; i++) af[i] = *(const f16x8*)&lA[cur][(wm*64 + i*16 + fm)*64 + ck];
      #pragma unroll
      for (int j = 0; j < 4; j++) bf[j] = *(const f16x8*)&lB[cur][(wn*64 + j*16 + fm)*64 + ck];
      #pragma unroll
      for (int i = 0; i < 4; i++)
        #pragma unroll
        for (int j = 0; j < 4; j++)
          acc[i][j] = __builtin_amdgcn_mfma_f32_16x16x32_f16(af[i], bf[j], acc[i][j], 0, 0, 0);
    }
    __syncthreads();
  }

  // C/D layout: col = lane&15, row = (lane>>4)*4 + reg
  const int colb = n0 + wn*64;
  const int rowb = m0 + wm*64;
  #pragma unroll
  for (int i = 0; i < 4; i++) {
    #pragma unroll
    for (int j = 0; j < 4; j++) {
      const int col = colb + j*16 + fm;
      const float bs = bias[col];
      #pragma unroll
      for (int r = 0; r < 4; r++) {
        const int row = rowb + i*16 + g4*4 + r;
        float v = acc[i][j][r] + bs;
        const size_t idx = (size_t)row * N + col;
        if constexpr (EPI == EPI_H)        { Ch[idx] = (f16)v; }
        else if constexpr (EPI == EPI_T)   { v = fmaxf(v, 0.f); Ch[idx] = (f16)v; }
        else if constexpr (EPI == EPI_RES) { v = fmaxf(v, 0.f); v += (float)Hin[idx]; Ch[idx] = (f16)v; }
        else                               { Cf[idx] = v; }
      }
    }
  }
}

// ------------- int8 S-GEMM: 128x128 tile, BK=128, LDS dbuf, 6 iters -------------
// Same 128 B/row geometry and swizzle as gemm_bt.
__global__ __launch_bounds__(256) void gemm_s8(
    const s8* __restrict__ A, const s8* __restrict__ B,
    float* __restrict__ partsum, float* __restrict__ partmax, float* __restrict__ diagv)
{
  __shared__ alignas(16) s8 lA[2][128*128];   // 32 KB
  __shared__ alignas(16) s8 lB[2][128*128];   // 32 KB
  __shared__ float redS[2][128], redM[2][128];
  const int K = OUTD;
  const int tid = threadIdx.x;
  const int wave = tid >> 6, lane = tid & 63;
  const int m0 = blockIdx.x * 128, n0 = blockIdx.y * 128;
  const int r8 = lane >> 3;
  const int c8 = lane & 7;
  const int cg = c8 ^ r8;
  const s8* gA = A + (size_t)(m0 + wave*32 + r8) * K + cg*16;
  const s8* gB = B + (size_t)(n0 + wave*32 + r8) * K + cg*16;
  const int wm = wave & 1, wn = wave >> 1;
  const int fm = lane & 15;
  const int g4 = lane >> 4;
  const int fsw = fm & 7;

  i32x4 acc[4][4];
  #pragma unroll
  for (int i = 0; i < 4; i++)
    #pragma unroll
    for (int j = 0; j < 4; j++) acc[i][j] = (i32x4){0,0,0,0};

  auto stage = [&](int buf, int it) {
    s8* dA = &lA[buf][wave*32*128];
    s8* dB = &lB[buf][wave*32*128];
    const s8* sA = gA + it*128;
    const s8* sB = gB + it*128;
    #pragma unroll
    for (int q = 0; q < 4; q++) {
      GL2LDS(sA + (size_t)q*8*K, dA + q*8*128);
      GL2LDS(sB + (size_t)q*8*K, dB + q*8*128);
    }
  };

  stage(0, 0);
  __syncthreads();
  const int iters = K / 128;   // 6
  for (int it = 0; it < iters; ++it) {
    const int cur = it & 1;
    if (it + 1 < iters) stage(cur ^ 1, it + 1);
    #pragma unroll
    for (int h = 0; h < 2; h++) {
      const int ck = ((h*4 + g4) ^ fsw) * 16;
      i32x4 af[4], bf[4];
      #pragma unroll
      for (int i = 0; i < 4; i++) af[i] = *(const i32x4*)&lA[cur][(wm*64 + i*16 + fm)*128 + ck];
      #pragma unroll
      for (int j = 0; j < 4; j++) bf[j] = *(const i32x4*)&lB[cur][(wn*64 + j*16 + fm)*128 + ck];
      #pragma unroll
      for (int i = 0; i < 4; i++)
        #pragma unroll
        for (int j = 0; j < 4; j++)
          acc[i][j] = __builtin_amdgcn_mfma_i32_16x16x64_i8(af[i], bf[j], acc[i][j], 0, 0, 0);
    }
    __syncthreads();
  }

  if (m0 == n0) {
    #pragma unroll
    for (int i = 0; i < 4; i++)
      #pragma unroll
      for (int j = 0; j < 4; j++) {
        const int col = n0 + wn*64 + j*16 + fm;
        #pragma unroll
        for (int r = 0; r < 4; r++) {
          const int row = m0 + wm*64 + i*16 + g4*4 + r;
          if (row == col) diagv[row] = (float)acc[i][j][r] * CSC;
        }
      }
  }
  #pragma unroll
  for (int i = 0; i < 4; i++) {
    #pragma unroll
    for (int r = 0; r < 4; r++) {
      const float a0 = (float)acc[i][0][r] * CSC;
      const float a1 = (float)acc[i][1][r] * CSC;
      const float a2 = (float)acc[i][2][r] * CSC;
      const float a3 = (float)acc[i][3][r] * CSC;
      float s  = exp2f(a0) + exp2f(a1) + exp2f(a2) + exp2f(a3);
      float mx = fmaxf(fmaxf(a0, a1), fmaxf(a2, a3));
      #pragma unroll
      for (int d = 1; d < 16; d <<= 1) {
        s  += __shfl_xor(s, d, 64);
        mx  = fmaxf(mx, __shfl_xor(mx, d, 64));
      }
      if (fm == 0) { const int lrow = wm*64 + i*16 + g4*4 + r; redS[wn][lrow] = s; redM[wn][lrow] = mx; }
    }
  }
  __syncthreads();
  if (tid < 128) {
    const float sa = redS[0][tid] + redS[1][tid];
    const float ma = fmaxf(redM[0][tid], redM[1][tid]);
    const size_t p = (size_t)blockIdx.y * BSZ + m0 + tid;
    partsum[p] = sa; partmax[p] = ma;
  }
}

// ---------------- final reduce + inlined finalize ----------------
__global__ __launch_bounds__(256) void reduce_rows(const float* __restrict__ partsum,
    const float* __restrict__ partmax, const float* __restrict__ diagv,
    float* __restrict__ accum, float* __restrict__ out) {
  __shared__ float sm[4];
  const int row = blockIdx.x*256 + threadIdx.x;
  float s = 0.f, mx = -1e30f;
  for (int i = 0; i < 64; i++) {
    s  += partsum[(size_t)i*BSZ + row];
    mx  = fmaxf(mx, partmax[(size_t)i*BSZ + row]);
  }
  const float dgs  = diagv[row];
  const float corr = (dgs >= mx) ? 1.f : 0.f;
  const float lse  = logf(s);
  const float dg   = dgs * LN2;
  const float lse_s = blk_sum256(lse, sm);
  const float dg_s  = blk_sum256(dg, sm);
  const float c_s   = blk_sum256(corr, sm);
  if (threadIdx.x == 0) {
    atomicAdd(&accum[0], lse_s);
    atomicAdd(&accum[1], dg_s);
    atomicAdd(&accum[2], c_s);
    __threadfence();
    const unsigned old = atomicAdd((unsigned*)&accum[3], 1u);
    if (old == gridDim.x - 1) {
      const float a0 = atomicAdd(&accum[0], 0.f);
      const float a1 = atomicAdd(&accum[1], 0.f);
      const float a2 = atomicAdd(&accum[2], 0.f);
      out[0] = a0 - a1;
      out[1] = a2 * (1.f / BSZ);
    }
  }
}

// ---------------- launch ----------------
extern "C" void kernel_launch(void* const* d_in, const int* in_sizes, int n_in,
                              void* d_out, int out_size, void* d_ws, size_t ws_size,
                              hipStream_t stream) {
  const float* inp  = (const float*)d_in[0];
  const float* y    = (const float*)d_in[1];
  const float* ln1g = (const float*)d_in[2];
  const float* ln1b = (const float*)d_in[3];
  const float* W1   = (const float*)d_in[4];
  const float* b1   = (const float*)d_in[5];
  const float* Wa   = (const float*)d_in[6];
  const float* ba   = (const float*)d_in[7];
  const float* Wb   = (const float*)d_in[8];
  const float* bb   = (const float*)d_in[9];
  const float* W2   = (const float*)d_in[10];
  const float* b2   = (const float*)d_in[11];
  const float* ln2g = (const float*)d_in[12];
  const float* ln2b = (const float*)d_in[13];
  float* out = (float*)d_out;

  char* ws = (char*)d_ws;
  f16*   XH   = (f16*)  (ws + OFF_XH);
  s8*    PN   = (s8*)   (ws + OFF_PN);
  s8*    YN   = (s8*)   (ws + OFF_YN);
  float* PSUM = (float*)(ws + OFF_PSUM);
  float* PMAX = (float*)(ws + OFF_PMAX);
  f16*   HB   = (f16*)  (ws + OFF_HB);
  f16*   T    = (f16*)  (ws + OFF_TT);
  float* PRE2 = (float*)(ws + OFF_TT);
  f16*   W1T  = (f16*)  (ws + OFF_W1T);
  f16*   WAT  = (f16*)  (ws + OFF_WAT);
  f16*   WBT  = (f16*)  (ws + OFF_WBT);
  f16*   W2T  = (f16*)  (ws + OFF_W2T);
  float* DIAG = (float*)(ws + OFF_DIAG);
  float* ACC  = (float*)(ws + OFF_ACC);

  transpose_all<<<5888, 256, 0, stream>>>(W1, Wa, Wb, W2, W1T, WAT, WBT, W2T);
  ln1_kernel<<<BSZ, 256, 0, stream>>>(inp, ln1g, ln1b, XH);

  gemm_bt<EPI_H><<<dim3(BSZ/128, HID/128), 256, 0, stream>>>(
      XH, W1T, INP, HID, b1, nullptr, HB, nullptr);

  for (int it = 0; it < 2; it++) {
    gemm_bt<EPI_T><<<dim3(BSZ/128, HID/128), 256, 0, stream>>>(
        HB, WAT, HID, HID, ba, nullptr, T, nullptr);
    gemm_bt<EPI_RES><<<dim3(BSZ/128, HID/128), 256, 0, stream>>>(
        T, WBT, HID, HID, bb, nullptr, HB, HB);
  }

  gemm_bt<EPI_P><<<dim3(BSZ/128, OUTD/128), 256, 0, stream>>>(
      HB, W2T, HID, OUTD, b2, PRE2, nullptr, nullptr);

  ln2_yn<<<2*BSZ, 256, 0, stream>>>(PRE2, ln2g, ln2b, y, out, PN, YN);

  hipMemsetAsync(ACC, 0, 4*sizeof(float), stream);

  gemm_s8<<<dim3(BSZ/128, BSZ/128), 256, 0, stream>>>(PN, YN, PSUM, PMAX, DIAG);

  reduce_rows<<<BSZ/256, 256, 0, stream>>>(PSUM, PMAX, DIAG, ACC, out + (size_t)BSZ*OUTD);
}